// Round 17
// baseline (607.433 us; speedup 1.0000x reference)
//
#include <hip/hip_runtime.h>
#include <cstdint>
#include <cstddef>

// PCFG inside algorithm. B=8, n=28, NT=32, T=64, ST=96.
// v9: fully-local row chain + table folding of rows 1..3 + pipelined core.
// Grid B*9 blocks, 1024 thr. Block r9==0: ROW role (whole width chain for its
// batch, all 32 symbols, DP state in LDS, finalize in-reg). r9 1..8: CORE
// role: 4 width-parity groups x 2 slices (512 pair-cols), k in 4..w-5, needs
// rows <= w-5 (4-round slack); 6 of them first BUILD one fold table each
// (F2..G4 from rows 1..3, uncached stores + ready flag).
// Width-w totals (per (s,a)):
//   k=0:F  k=1:F2  k=2:F3  k=3:F4 (left-row folds, right row from LDS)
//   k=w-1:G k=w-2:G2 k=w-3:G3 k=w-4:G4 (right-row folds)
//   k in 4..w-5: core partial (prefetched by waves 14-15 during round w-1)
// Tables in [s][a][32] layout (8xfloat4 dot). T1 (w==1 totals) precomputed in
// pack. Cross-block: ring rT (eB+bmax rows, depth 8), rN (core partials,
// depth 4), monotone flags. All cross-block data agent-scope (uncached).

#define NMAX 28
#define RT_SLOT 896
#define RN_SLOT 1728
#define TABSZ 28672

// row-role LDS (floats)
#define RW_TRI 0       // 378*32 = 12096
#define RW_BMX 12096   // 784
#define RW_CB  12880   // 2*864
// core-role LDS
#define CO_TRI 0       // 12096
#define CO_BMX 12096   // 784
#define CO_ELK 12880   // 3264
#define CO_ERK 16144   // 6528
#define CO_NUM 22672   // <=19*520 ush = 4940 f, alloc 5460
#define CO_RED 28132   // 16*896 ush = 7168 f
#define LDSF   35300

__device__ __forceinline__ int off32(int w, int n) {
    return (w - 1) * n - (w * (w - 1)) / 2;
}
__device__ __forceinline__ float gload(const float* p) {
    return __hip_atomic_load(p, __ATOMIC_RELAXED, __HIP_MEMORY_SCOPE_AGENT);
}
__device__ __forceinline__ void gstore(float* p, float v) {
    __hip_atomic_store(p, v, __ATOMIC_RELAXED, __HIP_MEMORY_SCOPE_AGENT);
}
__device__ __forceinline__ unsigned gloadu(const unsigned* p) {
    return __hip_atomic_load(p, __ATOMIC_RELAXED, __HIP_MEMORY_SCOPE_AGENT);
}
__device__ __forceinline__ void gstoreu(unsigned* p, unsigned v) {
    __hip_atomic_store(p, v, __ATOMIC_RELAXED, __HIP_MEMORY_SCOPE_AGENT);
}
__device__ __forceinline__ float b2f(unsigned short u) {
    return __uint_as_float(((unsigned)u) << 16);
}
__device__ __forceinline__ unsigned short f2b(float x) {
    unsigned u = __float_as_uint(x);
    return (unsigned short)((u + 0x7fffu + ((u >> 16) & 1u)) >> 16);
}
__device__ __forceinline__ float maxM(const float* bmx, int w, int s) {
    float M = -3.0e38f;
    for (int k = 0; k < w; ++k)
        M = fmaxf(M, bmx[k * NMAX + s] + bmx[(w - 1 - k) * NMAX + s + k + 1]);
    return M;
}
__device__ __forceinline__ float maxMc4(const float* bmx, int w, int s) {
    float M = -3.0e38f;
    for (int k = 4; k <= w - 5; ++k)
        M = fmaxf(M, bmx[k * NMAX + s] + bmx[(w - 1 - k) * NMAX + s + k + 1]);
    return M;
}
__device__ __forceinline__ float dot32(const float* tri, const float* tab) {
    float acc = 0.f;
    #pragma unroll
    for (int j = 0; j < 8; ++j) {
        float4 tv = *(const float4*)(tri + j * 4);
        float4 fv = *(const float4*)(tab + j * 4);
        acc = fmaf(tv.x, fv.x, acc); acc = fmaf(tv.y, fv.y, acc);
        acc = fmaf(tv.z, fv.z, acc); acc = fmaf(tv.w, fv.w, acc);
    }
    return acc;
}

// ---- prep: elT (l-major), bmax0, flags=0 ----
__global__ __launch_bounds__(256) void prep_kernel(const float* __restrict__ unary,
                                                   float* __restrict__ elT_g,
                                                   float* __restrict__ bmax0_g,
                                                   unsigned* __restrict__ flags,
                                                   int n) {
    int b = blockIdx.x, tid = threadIdx.x;
    if (tid < 32) gstoreu(&flags[b * 32 + tid], 0u);
    for (int pos = tid >> 6; pos < n; pos += 4) {
        int t = tid & 63;
        float v = unary[((size_t)(b * n) + pos) * 64 + t];
        float m = v;
        for (int off = 32; off > 0; off >>= 1) m = fmaxf(m, __shfl_xor(m, off, 64));
        elT_g[(size_t)b * 64 * n + t * n + pos] = __expf(v - m);
        if (t == 0) bmax0_g[b * 32 + pos] = m;
    }
}

// ---- pack: per (b,a): exp(rule) -> T1, F, G, ENa, ENb, ENc ----
__global__ __launch_bounds__(256) void pack_kernel(const float* __restrict__ rule,
                                                   const float* __restrict__ elT_g,
                                                   float* __restrict__ T1_g,
                                                   float* __restrict__ Ftab,
                                                   float* __restrict__ Gtab,
                                                   float* __restrict__ ENa_g,
                                                   float* __restrict__ ENb_g,
                                                   float* __restrict__ ENc_g,
                                                   int n) {
    __shared__ float sl[11008];   // 9216 exp slice + 64*28 elT
    int b = blockIdx.y, aa = blockIdx.x, tid = threadIdx.x;
    const float4* rs4 = (const float4*)(rule + (size_t)(b * 32 + aa) * 9216);
    for (int i = tid; i < 2304; i += 256) {
        float4 v = rs4[i];
        float4 o;
        o.x = __expf(v.x); o.y = __expf(v.y); o.z = __expf(v.z); o.w = __expf(v.w);
        ((float4*)sl)[i] = o;
    }
    for (int i = tid; i < 64 * n; i += 256)
        sl[9216 + i] = elT_g[(size_t)b * 64 * n + i];
    __syncthreads();
    const float* elt = sl + 9216;
    // T1[s][a] = sum_{l,r} elT[l][s] elT[r][s+1] expE[(32+l)][32+r]
    if (tid < (n - 1) * 8) {
        int s = tid >> 3, sub = tid & 7;
        float acc = 0.f;
        for (int l = sub * 8; l < sub * 8 + 8; ++l) {
            float el = elt[l * n + s];
            const float* row = sl + (32 + l) * 96 + 32;
            float inner = 0.f;
            for (int r = 0; r < 64; ++r)
                inner = fmaf(elt[r * n + s + 1], row[r], inner);
            acc = fmaf(el, inner, acc);
        }
        acc += __shfl_xor(acc, 1, 8);
        acc += __shfl_xor(acc, 2, 8);
        acc += __shfl_xor(acc, 4, 8);
        if (sub == 0) T1_g[(size_t)b * 864 + s * 32 + aa] = acc;
    }
    // F[s][a][r] = sum_l elT[l][s] expE[(32+l)][r]   (r in NT)
    for (int i = tid; i < 32 * n; i += 256) {
        int r = i & 31, s = i >> 5;
        float acc = 0.f;
        for (int l = 0; l < 64; ++l)
            acc = fmaf(elt[l * n + s], sl[(32 + l) * 96 + r], acc);
        Ftab[(size_t)b * TABSZ + (s * 32 + aa) * 32 + r] = acc;
    }
    // G[s'][a][l] = sum_r elT[r][s'] expE[l][32+r]   (l in NT)
    for (int i = tid; i < 32 * n; i += 256) {
        int l = i & 31, s = i >> 5;
        float acc = 0.f;
        for (int r = 0; r < 64; ++r)
            acc = fmaf(elt[r * n + s], sl[l * 96 + 32 + r], acc);
        Gtab[(size_t)b * TABSZ + (s * 32 + aa) * 32 + l] = acc;
    }
    // ENa[a][l*32+r], ENb[a][r*32+l], ENc c-packed
    for (int i = tid; i < 1024; i += 256) {
        ENa_g[(size_t)b * 32768 + aa * 1024 + i] = sl[(i >> 5) * 96 + (i & 31)];
        ENb_g[(size_t)b * 32768 + aa * 1024 + i] = sl[(i & 31) * 96 + (i >> 5)];
    }
    if (tid < 256) {
        int flat = tid * 4, l = flat >> 5, r = flat & 31;
        float4 o = *(const float4*)(sl + l * 96 + r);
        *(float4*)(ENc_g + ((size_t)(b * 256 + tid) * 32 + aa) * 4) = o;
    }
}

__global__ __launch_bounds__(1024, 1) void inside_kernel(
    const float* __restrict__ T1_g, const float* __restrict__ bmax0_g,
    float* __restrict__ tabs, const float* __restrict__ ENa_g,
    const float* __restrict__ ENb_g, const float* __restrict__ ENc_g,
    float* __restrict__ ringT, float* __restrict__ ringN,
    const float* __restrict__ root, float* __restrict__ out,
    unsigned* __restrict__ flags, int n, int B) {
    extern __shared__ float lds[];
    const int b = blockIdx.x / 9, r9 = blockIdx.x % 9;
    const int tid = threadIdx.x;
    unsigned* const fl = flags + b * 32;
    float* const rT = ringT + (size_t)b * 8 * RT_SLOT;
    float* const rN = ringN + (size_t)b * 4 * RN_SLOT;
    const size_t tb = (size_t)b * TABSZ;
    const size_t tstep = (size_t)B * TABSZ;

    if (r9 == 0) {
        // ================= ROW role =================
        if (tid < n) lds[RW_BMX + tid] = bmax0_g[b * 32 + tid];
        __syncthreads();

        for (int w = 1; w < n; ++w) {
            const int S = n - w;
            // gate on fold-table readiness (first use of each)
            if (w >= 3 && w <= 8) {
                if (tid < 64) {
                    while (gloadu(fl + 16 + (w - 3)) < 1u)
                        __builtin_amdgcn_s_sleep(8);
                }
                __syncthreads();
            }

            if (tid < S * 32) {
                const int s = tid >> 5, a = tid & 31;
                float Mloc = 0.f, t2;
                if (w == 1) {
                    t2 = T1_g[(size_t)b * 864 + tid];
                    if (a == 0) Mloc = maxM(lds + RW_BMX, 1, s);
                } else {
                    float gv = 0.f;
                    if (a < 9) {
                        Mloc = maxM(lds + RW_BMX, w, s);
                        const float* B_ = lds + RW_BMX;
                        float x = -3.0e38f;
                        if      (a == 0) x = B_[s] + B_[(w - 1) * NMAX + s + 1];
                        else if (a == 1) x = B_[(w - 1) * NMAX + s] + B_[s + w];
                        else if (a == 2 && w >= 3) x = B_[NMAX + s] + B_[(w - 2) * NMAX + s + 2];
                        else if (a == 3 && w >= 4) x = B_[(w - 2) * NMAX + s] + B_[NMAX + s + w - 1];
                        else if (a == 4 && w >= 5) x = B_[2 * NMAX + s] + B_[(w - 3) * NMAX + s + 3];
                        else if (a == 5 && w >= 6) x = B_[(w - 3) * NMAX + s] + B_[2 * NMAX + s + w - 2];
                        else if (a == 6 && w >= 7) x = B_[3 * NMAX + s] + B_[(w - 4) * NMAX + s + 4];
                        else if (a == 7 && w >= 8) x = B_[(w - 4) * NMAX + s] + B_[3 * NMAX + s + w - 3];
                        else if (a == 8 && w >= 9) x = maxMc4(B_, w, s);
                        gv = (x > -1.0e38f) ? __expf(x - Mloc) : 0.f;
                    }
                    float g0 = __shfl(gv, 0, 32), gw = __shfl(gv, 1, 32);
                    float g1 = __shfl(gv, 2, 32), g2x = __shfl(gv, 3, 32);
                    float g3 = __shfl(gv, 4, 32), g3x = __shfl(gv, 5, 32);
                    float g4 = __shfl(gv, 6, 32), g4x = __shfl(gv, 7, 32);
                    float gc = __shfl(gv, 8, 32);
                    const float* TRIp = lds + RW_TRI;
                    const size_t ca = (size_t)(s * 32 + a) * 32;
                    t2 = g0 * dot32(TRIp + (off32(w - 1, n) + s + 1) * 32,
                                    tabs + 0 * tstep + tb + ca)
                       + gw * dot32(TRIp + (off32(w - 1, n) + s) * 32,
                                    tabs + 1 * tstep + tb + (size_t)((s + w) * 32 + a) * 32);
                    if (w >= 3)
                        t2 = fmaf(g1, dot32(TRIp + (off32(w - 2, n) + s + 2) * 32,
                                            tabs + 2 * tstep + tb + ca), t2);
                    if (w >= 4)
                        t2 = fmaf(g2x, dot32(TRIp + (off32(w - 2, n) + s) * 32,
                                             tabs + 3 * tstep + tb + (size_t)((s + w - 1) * 32 + a) * 32), t2);
                    if (w >= 5)
                        t2 = fmaf(g3, dot32(TRIp + (off32(w - 3, n) + s + 3) * 32,
                                            tabs + 4 * tstep + tb + ca), t2);
                    if (w >= 6)
                        t2 = fmaf(g3x, dot32(TRIp + (off32(w - 3, n) + s) * 32,
                                             tabs + 5 * tstep + tb + (size_t)((s + w - 2) * 32 + a) * 32), t2);
                    if (w >= 7)
                        t2 = fmaf(g4, dot32(TRIp + (off32(w - 4, n) + s + 4) * 32,
                                            tabs + 6 * tstep + tb + ca), t2);
                    if (w >= 8)
                        t2 = fmaf(g4x, dot32(TRIp + (off32(w - 4, n) + s) * 32,
                                             tabs + 7 * tstep + tb + (size_t)((s + w - 3) * 32 + a) * 32), t2);
                    if (w >= 9)
                        t2 = fmaf(gc, lds[RW_CB + (w & 1) * 864 + tid], t2);
                }
                // finalize in-reg
                float m2 = t2;
                for (int off = 16; off > 0; off >>= 1)
                    m2 = fmaxf(m2, __shfl_xor(m2, off, 32));
                float eB = t2 / m2;
                lds[RW_TRI + (off32(w, n) + s) * 32 + a] = eB;
                gstore(rT + (size_t)(w & 7) * RT_SLOT + tid, eB);
                if (a == 0) {
                    float bm = __logf(m2) + Mloc;
                    lds[RW_BMX + w * NMAX + s] = bm;
                    gstore(rT + (size_t)(w & 7) * RT_SLOT + 864 + s, bm);
                }
            } else if (tid >= 896) {
                // prefetch core(w+1) (waves 14-15)
                const int wn = w + 1;
                if (wn >= 9 && wn < n) {
                    const int grp = wn & 3, pre = tid - 896;
                    const unsigned* f0 = fl + 8 + grp * 2;
                    for (;;) {
                        if (gloadu(f0) >= (unsigned)wn && gloadu(f0 + 1) >= (unsigned)wn)
                            break;
                        __builtin_amdgcn_s_sleep(8);
                    }
                    const int Sn = n - wn;
                    const float* src = rN + (size_t)(wn & 3) * RN_SLOT;
                    for (int e = pre; e < Sn * 32; e += 128)
                        lds[RW_CB + (wn & 1) * 864 + e] =
                            gload(src + e * 2) + gload(src + e * 2 + 1);
                }
            }
            __syncthreads();
            if (tid == 0) gstoreu(fl, (unsigned)w);
        }

        // epilogue
        if (tid < 32) {
            float eB = lds[RW_TRI + off32(n - 1, n) * 32 + tid];
            float v = eB * __expf(root[b * 32 + tid]);
            for (int off = 16; off > 0; off >>= 1) v += __shfl_xor(v, off, 32);
            if (tid == 0) out[b] = lds[RW_BMX + (n - 1) * NMAX] + __logf(v);
        }
    } else {
        // ================= CORE role =================
        const int idx = r9 - 1, grp = idx >> 1, sl = idx & 1;
        // builder assignment: idx {0,1,6,7,4,5} -> tables {F2,G2,F3,G3,F4,G4}
        int tableId = -1;
        if (idx == 0) tableId = 0; else if (idx == 1) tableId = 1;
        else if (idx == 6) tableId = 2; else if (idx == 7) tableId = 3;
        else if (idx == 4) tableId = 4; else if (idx == 5) tableId = 5;

        if (tableId >= 0) {
            const int foldRow = 1 + (tableId >> 1);
            const bool isF = (tableId & 1) == 0;
            if (tid < 64) {
                while (gloadu(fl) < (unsigned)foldRow) __builtin_amdgcn_s_sleep(8);
            }
            __syncthreads();
            const int cntE = (n - foldRow) * 32;
            for (int e = tid; e < cntE; e += 1024)
                lds[CO_TRI + e] = gload(rT + (size_t)(foldRow & 7) * RT_SLOT + e);
            __syncthreads();
            const int maxSx = n - foldRow;
            if (tid < maxSx * 32) {
                const int sx = tid >> 5, a = tid & 31;
                const float* EN = (isF ? ENa_g : ENb_g) + (size_t)b * 32768 + a * 1024;
                float4 acc[8];
                #pragma unroll
                for (int j = 0; j < 8; ++j) acc[j] = make_float4(0.f, 0.f, 0.f, 0.f);
                for (int q = 0; q < 32; ++q) {
                    float e = lds[CO_TRI + sx * 32 + q];
                    const float4* ev = (const float4*)(EN + q * 32);
                    #pragma unroll
                    for (int j = 0; j < 8; ++j) {
                        float4 v = ev[j];
                        acc[j].x = fmaf(e, v.x, acc[j].x);
                        acc[j].y = fmaf(e, v.y, acc[j].y);
                        acc[j].z = fmaf(e, v.z, acc[j].z);
                        acc[j].w = fmaf(e, v.w, acc[j].w);
                    }
                }
                float* dp = tabs + (size_t)(2 + tableId) * tstep + tb +
                            (size_t)(sx * 32 + a) * 32;
                #pragma unroll
                for (int j = 0; j < 8; ++j) {
                    gstore(dp + j * 4 + 0, acc[j].x);
                    gstore(dp + j * 4 + 1, acc[j].y);
                    gstore(dp + j * 4 + 2, acc[j].z);
                    gstore(dp + j * 4 + 3, acc[j].w);
                }
            }
            __syncthreads();
            if (tid == 0) gstoreu(fl + 16 + tableId, 1u);
        }

        // E regs for slice
        float4 e4[4];
        {
            int g = tid >> 5, a = tid & 31;
            #pragma unroll
            for (int i = 0; i < 4; ++i)
                e4[i] = *(const float4*)(ENc_g +
                    ((size_t)(b * 256 + sl * 128 + g * 4 + i) * 32 + a) * 4);
        }
        int lastFin = 3;
        const int W0 = (grp == 0) ? 12 : 8 + grp;
        for (int W = W0; W < n; W += 4) {
            const int S = n - W, Sp2 = S | 1;
            const int cnt = W - 8;
            int q4 = (cnt + 3) >> 2; if (!(q4 & 1)) ++q4;
            const int K4 = 4 * q4;
            if (tid < 64) {
                while (gloadu(fl) < (unsigned)(W - 5)) __builtin_amdgcn_s_sleep(8);
            }
            __syncthreads();
            // load rows lastFin+1..W-5 (prefetch all, then write LDS)
            {
                const int nf = (W - 5) - lastFin;   // <= 4
                float ev[4], bv[4];
                for (int i = 0; i < nf; ++i) {
                    int wf = lastFin + 1 + i;
                    ev[i] = (tid < (n - wf) * 32)
                        ? gload(rT + (size_t)(wf & 7) * RT_SLOT + tid) : 0.f;
                    bv[i] = (tid < (n - wf))
                        ? gload(rT + (size_t)(wf & 7) * RT_SLOT + 864 + tid) : 0.f;
                }
                for (int i = 0; i < nf; ++i) {
                    int wf = lastFin + 1 + i;
                    if (tid < (n - wf) * 32)
                        lds[CO_TRI + (off32(wf, n) + (tid >> 5)) * 32 + (tid & 31)] = ev[i];
                    if (tid < (n - wf)) lds[CO_BMX + wf * NMAX + tid] = bv[i];
                }
                lastFin = W - 5;
            }
            __syncthreads();
            // A3: k-packed ELK/ERK (g folded, local Mc4)
            if (tid < S * 32) {
                int s = tid >> 5, sym = tid & 31;
                float Mc = maxMc4(lds + CO_BMX, W, s);
                int eo = (sym * Sp2 + s) * K4;
                for (int k = 4; k <= W - 5; ++k)
                    lds[CO_ERK + eo + k - 4] =
                        lds[CO_TRI + (off32(W - 1 - k, n) + s + k + 1) * 32 + sym] *
                        __expf(lds[CO_BMX + k * NMAX + s] +
                               lds[CO_BMX + (W - 1 - k) * NMAX + s + k + 1] - Mc);
                for (int j = cnt; j < K4; ++j) lds[CO_ERK + eo + j] = 0.f;
                if (sym < 16) {
                    int lo = (sym * Sp2 + s) * K4;
                    int gl = sl * 16 + sym;
                    for (int k = 4; k <= W - 5; ++k)
                        lds[CO_ELK + lo + k - 4] =
                            lds[CO_TRI + (off32(k, n) + s) * 32 + gl];
                    for (int j = cnt; j < K4; ++j) lds[CO_ELK + lo + j] = 0.f;
                }
            }
            __syncthreads();
            // C: numer (512 cols) -> bf16
            {
                int cL = tid & 511, sh = tid >> 9;
                int lloc = cL >> 5, r = cL & 31;
                unsigned short* np = (unsigned short*)(lds + CO_NUM);
                for (int s = sh; s < S; s += 2) {
                    const float* ep = lds + CO_ELK + (lloc * Sp2 + s) * K4;
                    const float* rp = lds + CO_ERK + (r * Sp2 + s) * K4;
                    float acc = 0.f;
                    for (int j = 0; j < K4; j += 4) {
                        float4 a4 = *(const float4*)(ep + j);
                        float4 b4 = *(const float4*)(rp + j);
                        acc = fmaf(a4.x, b4.x, fmaf(a4.y, b4.y,
                              fmaf(a4.z, b4.z, fmaf(a4.w, b4.w, acc))));
                    }
                    np[s * 520 + cL] = f2b(acc);
                }
            }
            __syncthreads();
            // D: contract vs E regs (4 c4/thread), wave-pair reduce
            {
                const char* nbase = (const char*)(lds + CO_NUM);
                unsigned short* red = (unsigned short*)(lds + CO_RED);
                int g = tid >> 5, a = tid & 31, wv = tid >> 6;
                bool low = (tid & 32) == 0;
                for (int s = 0; s < S; ++s) {
                    uint4 u0 = *(const uint4*)(nbase + s * 1040 + g * 32);
                    uint4 u1 = *(const uint4*)(nbase + s * 1040 + g * 32 + 16);
                    #define LOu(x) __uint_as_float((x) << 16)
                    #define HIu(x) __uint_as_float((x) & 0xffff0000u)
                    float acc = LOu(u0.x) * e4[0].x + HIu(u0.x) * e4[0].y
                              + LOu(u0.y) * e4[0].z + HIu(u0.y) * e4[0].w
                              + LOu(u0.z) * e4[1].x + HIu(u0.z) * e4[1].y
                              + LOu(u0.w) * e4[1].z + HIu(u0.w) * e4[1].w
                              + LOu(u1.x) * e4[2].x + HIu(u1.x) * e4[2].y
                              + LOu(u1.y) * e4[2].z + HIu(u1.y) * e4[2].w
                              + LOu(u1.z) * e4[3].x + HIu(u1.z) * e4[3].y
                              + LOu(u1.w) * e4[3].z + HIu(u1.w) * e4[3].w;
                    #undef LOu
                    #undef HIu
                    acc += __shfl_xor(acc, 32, 64);
                    if (low) red[wv * 896 + s * 32 + a] = f2b(acc);
                }
            }
            __syncthreads();
            // E: publish slice partial
            if (tid < S * 32) {
                const unsigned short* red = (const unsigned short*)(lds + CO_RED);
                float t = 0.f;
                for (int g2 = 0; g2 < 16; ++g2) t += b2f(red[g2 * 896 + tid]);
                gstore(rN + (size_t)(W & 3) * RN_SLOT + (size_t)tid * 2 + sl, t);
            }
            __syncthreads();
            if (tid == 0) gstoreu(fl + 8 + grp * 2 + sl, (unsigned)W);
        }
    }
}

extern "C" void kernel_launch(void* const* d_in, const int* in_sizes, int n_in,
                              void* d_out, int out_size, void* d_ws, size_t ws_size,
                              hipStream_t stream) {
    const float* unary = (const float*)d_in[0]; // B,n,64
    const float* rule  = (const float*)d_in[1]; // B,32,96,96
    const float* root  = (const float*)d_in[2]; // B,32
    float* out = (float*)d_out;

    const int B = in_sizes[2] / 32;
    int n = in_sizes[0] / (B * 64);

    float* ws = (float*)d_ws;
    float* elT_g = ws;                                   // B*64*n
    float* bmax0 = elT_g + (size_t)B * 64 * n;           // B*32
    float* T1_g  = bmax0 + (size_t)B * 32;               // B*864
    float* tabs  = T1_g + (size_t)B * 864;               // 8*B*TABSZ
    float* ENa_g = tabs + (size_t)8 * B * TABSZ;         // B*32768
    float* ENb_g = ENa_g + (size_t)B * 32768;            // B*32768
    float* ENc_g = ENb_g + (size_t)B * 32768;            // B*32768
    float* ringT = ENc_g + (size_t)B * 32768;            // B*8*RT_SLOT
    float* ringN = ringT + (size_t)B * 8 * RT_SLOT;      // B*4*RN_SLOT
    unsigned* flags = (unsigned*)(ringN + (size_t)B * 4 * RN_SLOT); // B*32

    prep_kernel<<<dim3(B), 256, 0, stream>>>(unary, elT_g, bmax0, flags, n);
    pack_kernel<<<dim3(32, B), 256, 0, stream>>>(rule, elT_g, T1_g,
                                                 tabs + (size_t)0,
                                                 tabs + (size_t)B * TABSZ,
                                                 ENa_g, ENb_g, ENc_g, n);

    hipFuncSetAttribute((const void*)inside_kernel,
                        hipFuncAttributeMaxDynamicSharedMemorySize, LDSF * 4);
    void* args[] = {
        (void*)&T1_g, (void*)&bmax0, (void*)&tabs, (void*)&ENa_g, (void*)&ENb_g,
        (void*)&ENc_g, (void*)&ringT, (void*)&ringN, (void*)&root, (void*)&out,
        (void*)&flags, (void*)&n, (void*)&B
    };
    hipLaunchCooperativeKernel((void*)inside_kernel, dim3(B * 9), dim3(1024),
                               args, LDSF * 4, stream);
}